// Round 9
// baseline (122.948 us; speedup 1.0000x reference)
//
#include <hip/hip_runtime.h>
#include <hip/hip_bf16.h>
#include <stddef.h>

#define B_SZ   32
#define N_SZ   512
#define M_SZ   512
#define D_SZ   256
#define NSLAB  192           // chunk-skew slabs: s = (j>>2) + (i>>3), 0..190 (+1 pad)
#define SLAB_F4 512          // 2048 f32 per slab = 512 float4
#define BIGF   1e10f

typedef __attribute__((ext_vector_type(8))) short short8;
typedef __attribute__((ext_vector_type(4))) float f32x4;

__device__ __forceinline__ unsigned pack_bf16(float lo, float hi) {
    unsigned short a = __builtin_bit_cast(unsigned short, __float2bfloat16(lo));
    unsigned short b = __builtin_bit_cast(unsigned short, __float2bfloat16(hi));
    return (unsigned)a | ((unsigned)b << 16);
}

// load 8 consecutive f32 and convert to a bf16 short8 (MFMA fragment)
__device__ __forceinline__ short8 load_cvt_bf16(const float* __restrict__ p) {
    float4 a = *(const float4*)p;
    float4 b = *(const float4*)(p + 4);
    uint4 u;
    u.x = pack_bf16(a.x, a.y);
    u.y = pack_bf16(a.z, a.w);
    u.z = pack_bf16(b.x, b.y);
    u.w = pack_bf16(b.z, b.w);
    return __builtin_bit_cast(short8, u);
}

// ---------------------------------------------------------------------------
// teacher (B,M,1024) -> ybf (B,M,256) bf16 (mean of 4) + y2 row norms (f32).
__global__ void reduce_kernel(const float* __restrict__ t, ushort* __restrict__ ybf,
                              float* __restrict__ y2) {
    const int row = blockIdx.x;            // 0..16383
    const int c   = threadIdx.x;           // 0..255
    float4 v = *((const float4*)t + (size_t)row * 256 + c);
    float m = (v.x + v.y + v.z + v.w) * 0.25f;
    ybf[(size_t)row * 256 + c] = __builtin_bit_cast(unsigned short, __float2bfloat16(m));
    float s = m * m;
    #pragma unroll
    for (int o = 32; o > 0; o >>= 1) s += __shfl_down(s, o);
    __shared__ float acc4[4];
    if ((c & 63) == 0) acc4[c >> 6] = s;
    __syncthreads();
    if (c == 0) y2[row] = (acc4[0] + acc4[1]) + (acc4[2] + acc4[3]);
}

// ---------------------------------------------------------------------------
// x row squared norms only (x consumed as f32 directly by gemm now).
__global__ void rowsq_kernel(const float* __restrict__ src, float* __restrict__ dst) {
    int wave = threadIdx.x >> 6;
    int lane = threadIdx.x & 63;
    int row  = blockIdx.x * 4 + wave;
    const float4* r4 = (const float4*)(src + (size_t)row * D_SZ);
    float4 v = r4[lane];
    float s = v.x*v.x + v.y*v.y + v.z*v.z + v.w*v.w;
    #pragma unroll
    for (int o = 32; o > 0; o >>= 1) s += __shfl_down(s, o);
    if (lane == 0) dst[row] = s;
}

// ---------------------------------------------------------------------------
// bf16 MFMA distance GEMM (no LDS), chunk-skew F32 output:
//   element ((b*NSLAB + s)*2048) + L*32 + c*8 + r  holds D(i = 8L+r, j = 4(s-L)+c)
// i.e. s = (j>>2) + (i>>3), L = i>>3, c = j&3, r = i&7.
// A-operand converted f32->bf16 in-register (x has no bf16 copy anymore).
__global__ void __launch_bounds__(256) gemm_kernel(const float* __restrict__ x,
                                                   const ushort* __restrict__ ybf,
                                                   const float* __restrict__ x2,
                                                   const float* __restrict__ y2,
                                                   float* __restrict__ Dskew) {
    const int b    = blockIdx.z;
    const int bi   = blockIdx.x;
    const int bj   = blockIdx.y;
    const int w    = threadIdx.x >> 6;
    const int lane = threadIdx.x & 63;
    const int wi   = w & 1, wj = w >> 1;
    const int m    = lane & 15, g = lane >> 4;

    const int i0 = bi * 128 + wi * 64;
    const int j0 = bj * 128 + wj * 64;

    const float*  xb = x   + ((size_t)b * N_SZ + i0 + m) * D_SZ + 8 * g;
    const ushort* yb = ybf + ((size_t)b * M_SZ + j0 + m) * D_SZ + 8 * g;

    f32x4 acc[4][4] = {};

    for (int k0 = 0; k0 < D_SZ; k0 += 32) {
        short8 av[4], bv[4];
        #pragma unroll
        for (int f = 0; f < 4; ++f) {
            av[f] = load_cvt_bf16(xb + (size_t)f * 16 * D_SZ + k0);
            bv[f] = *(const short8*)(yb + (size_t)f * 16 * D_SZ + k0);
        }
        #pragma unroll
        for (int fi = 0; fi < 4; ++fi)
            #pragma unroll
            for (int fj = 0; fj < 4; ++fj)
                acc[fi][fj] = __builtin_amdgcn_mfma_f32_16x16x32_bf16(
                                  av[fi], bv[fj], acc[fi][fj], 0, 0, 0);
    }

    const size_t bbase = (size_t)b * NSLAB * 2048;
    #pragma unroll
    for (int fi = 0; fi < 4; ++fi) {
        const int ib = i0 + fi * 16 + 4 * g;          // 4 consecutive i in one 8-block
        const int L  = ib >> 3;
        const float4 xv = *(const float4*)(x2 + b * N_SZ + ib);
        #pragma unroll
        for (int fj = 0; fj < 4; ++fj) {
            const int j = j0 + fj * 16 + m;
            const float y2v = y2[b * M_SZ + j];
            float4 o;
            o.x = (xv.x + y2v) - 2.0f * acc[fi][fj][0];
            o.y = (xv.y + y2v) - 2.0f * acc[fi][fj][1];
            o.z = (xv.z + y2v) - 2.0f * acc[fi][fj][2];
            o.w = (xv.w + y2v) - 2.0f * acc[fi][fj][3];
            size_t off = bbase + (size_t)((j >> 2) + L) * 2048
                       + (size_t)L * 32 + (j & 3) * 8 + (ib & 7);
            *(float4*)(Dskew + off) = o;
        }
    }
}

// ---------------------------------------------------------------------------
// DTW hard-min DP, min3 form, 4-column chunks, anti-diagonal SSA dataflow,
// F32 slabs: d-values come straight from the load registers (zero unpack ALU).
// Lane L owns rows 8L..8L+7; chunk t = s - L at step s. 2-deep slab prefetch.
// PHASE: 0 = head (s 0..63, t>=0 guard + t==0 corner), 1 = middle (all active),
//        2 = tail (s 128..191, t<=127 guard).
template <int PHASE>
__device__ __forceinline__ void dtw_step(int s, int lane,
    const float4* __restrict__ base, float4 (&q)[8],
    float (&V)[8], float (&top)[4], float& diag0)
{
    // d[c][r] = q[2c + (r>>2)][r&3]  (all compile-time indices)
    float d[4][8];
    #pragma unroll
    for (int c = 0; c < 4; ++c) {
        d[c][0] = q[2*c].x;   d[c][1] = q[2*c].y;
        d[c][2] = q[2*c].z;   d[c][3] = q[2*c].w;
        d[c][4] = q[2*c+1].x; d[c][5] = q[2*c+1].y;
        d[c][6] = q[2*c+1].z; d[c][7] = q[2*c+1].w;
    }
    // prefetch slab s+2 into q (2-deep pipeline)
    int sp = s + 2; if (sp > NSLAB - 1) sp = NSLAB - 1;
    const float4* pp = base + (size_t)sp * SLAB_F4;
    #pragma unroll
    for (int u = 0; u < 8; ++u) q[u] = pp[u];

    float sv0 = V[7], sv1 = V[7], sv2 = V[7], sv3 = V[7];

    bool act;
    if (PHASE == 0)      act = (s >= lane);          // t >= 0  (t <= 63 auto)
    else if (PHASE == 1) act = true;                 // 1 <= t <= 127 guaranteed
    else                 act = (s - lane <= 127);    // t <= 127 (t >= 65 auto)

    if (act) {
        float dg0 = diag0;
        if (PHASE == 0) {
            if (s == lane) dg0 = (lane == 0) ? 0.0f : BIGF;   // chunk 0: C(.,-1)=BIG; (0,0)=0
        }
        float n[8][4];
        #pragma unroll
        for (int t = 0; t < 11; ++t) {
            #pragma unroll
            for (int c = 0; c < 4; ++c) {
                const int r = t - c;
                if (r >= 0 && r < 8) {
                    float A, Bv, Cv;
                    if (r == 0) { A = top[c]; Cv = (c == 0) ? dg0 : top[c-1]; }
                    else        { A = n[r-1][c]; Cv = (c == 0) ? V[r-1] : n[r-1][c-1]; }
                    Bv = (c == 0) ? V[r] : n[r][c-1];
                    n[r][c] = d[c][r] + fminf(fminf(A, Bv), Cv);
                }
            }
        }
        #pragma unroll
        for (int r = 0; r < 8; ++r) V[r] = n[r][3];
        sv0 = n[7][0]; sv1 = n[7][1]; sv2 = n[7][2]; sv3 = n[7][3];
    }

    // boundary exchange for next step (all lanes execute)
    diag0 = top[3];
    float t0 = __shfl_up(sv0, 1);
    float t1 = __shfl_up(sv1, 1);
    float t2 = __shfl_up(sv2, 1);
    float t3 = __shfl_up(sv3, 1);
    const bool l0 = (lane == 0);
    top[0] = l0 ? BIGF : t0;
    top[1] = l0 ? BIGF : t1;
    top[2] = l0 ? BIGF : t2;
    top[3] = l0 ? BIGF : t3;
}

__global__ void __launch_bounds__(64) dtw_kernel(const float* __restrict__ Dskew,
                                                 float* __restrict__ partial) {
    const int lane = threadIdx.x;
    const int b    = blockIdx.x;
    const float4* base = (const float4*)(Dskew + (size_t)b * NSLAB * 2048) + lane * 8;

    float V[8];
    #pragma unroll
    for (int r = 0; r < 8; ++r) V[r] = BIGF;
    float top[4] = {BIGF, BIGF, BIGF, BIGF};
    float diag0  = BIGF;    // (overridden at t==0; lane0 corner handled there)

    float4 qA[8], qB[8];
    #pragma unroll
    for (int u = 0; u < 8; ++u) qA[u] = base[u];
    #pragma unroll
    for (int u = 0; u < 8; ++u) qB[u] = base[SLAB_F4 + u];

    for (int s = 0; s < 64; s += 2) {      // head: t>=0 guard + t==0 corner
        dtw_step<0>(s + 0, lane, base, qA, V, top, diag0);
        dtw_step<0>(s + 1, lane, base, qB, V, top, diag0);
    }
    for (int s = 64; s < 128; s += 2) {    // middle: all lanes active
        dtw_step<1>(s + 0, lane, base, qA, V, top, diag0);
        dtw_step<1>(s + 1, lane, base, qB, V, top, diag0);
    }
    for (int s = 128; s < 192; s += 2) {   // tail: t<=127 guard (s=191 is a pad step)
        dtw_step<2>(s + 0, lane, base, qA, V, top, diag0);
        dtw_step<2>(s + 1, lane, base, qB, V, top, diag0);
    }

    if (lane == 63) partial[b] = V[7];     // cell (511, 511)
}

// ---------------------------------------------------------------------------
__global__ void finalize_kernel(const float* __restrict__ partial, float* __restrict__ out) {
    int lane = threadIdx.x;
    float v = (lane < B_SZ) ? partial[lane] : 0.0f;
    #pragma unroll
    for (int o = 32; o > 0; o >>= 1) v += __shfl_down(v, o);
    if (lane == 0) out[0] = v * (1.0f / B_SZ);
}

// ---------------------------------------------------------------------------
extern "C" void kernel_launch(void* const* d_in, const int* in_sizes, int n_in,
                              void* d_out, int out_size, void* d_ws, size_t ws_size,
                              hipStream_t stream) {
    const float* x  = (const float*)d_in[0];   // (32,512,256)
    const float* te = (const float*)d_in[1];   // (32,512,1024)
    float* out = (float*)d_out;

    char* ws = (char*)d_ws;
    float*  Dskew = (float*)(ws);                                    // 32*192*2048 f32 = 50.3MB
    ushort* ybf   = (ushort*)(ws + (size_t)B_SZ * NSLAB * 2048 * 4); // 32*512*256 bf16 = 8.4MB
    float*  x2    = (float*)(ybf + (size_t)B_SZ * M_SZ * D_SZ);
    float*  y2    = x2 + B_SZ * N_SZ;
    float*  part  = y2 + B_SZ * M_SZ;

    reduce_kernel<<<B_SZ * M_SZ, 256, 0, stream>>>(te, ybf, y2);
    rowsq_kernel<<<(B_SZ * N_SZ) / 4, 256, 0, stream>>>(x, x2);
    gemm_kernel<<<dim3(N_SZ/128, M_SZ/128, B_SZ), 256, 0, stream>>>(x, ybf, x2, y2, Dskew);
    dtw_kernel<<<B_SZ, 64, 0, stream>>>(Dskew, part);
    finalize_kernel<<<1, 64, 0, stream>>>(part, out);
}

// Round 10
// 121.968 us; speedup vs baseline: 1.0080x; 1.0080x over previous
//
#include <hip/hip_runtime.h>
#include <hip/hip_bf16.h>
#include <stddef.h>

#define B_SZ   32
#define N_SZ   512
#define M_SZ   512
#define D_SZ   256
#define NSLAB  128           // 8x8-chunk skew slabs: s = (i>>3) + (j>>3), 0..126 (+1 pad)
#define SLAB_U4 512          // 4096 bf16 per slab = 512 uint4
#define BIGF   1e10f

typedef __attribute__((ext_vector_type(8))) short short8;
typedef __attribute__((ext_vector_type(4))) float f32x4;

__device__ __forceinline__ unsigned pack_bf16(float lo, float hi) {
    unsigned short a = __builtin_bit_cast(unsigned short, __float2bfloat16(lo));
    unsigned short b = __builtin_bit_cast(unsigned short, __float2bfloat16(hi));
    return (unsigned)a | ((unsigned)b << 16);
}

// load 8 consecutive f32 and convert to a bf16 short8 (MFMA fragment)
__device__ __forceinline__ short8 load_cvt_bf16(const float* __restrict__ p) {
    float4 a = *(const float4*)p;
    float4 b = *(const float4*)(p + 4);
    uint4 u;
    u.x = pack_bf16(a.x, a.y);
    u.y = pack_bf16(a.z, a.w);
    u.z = pack_bf16(b.x, b.y);
    u.w = pack_bf16(b.z, b.w);
    return __builtin_bit_cast(short8, u);
}

// ---------------------------------------------------------------------------
// teacher (B,M,1024) -> ybf (B,M,256) bf16 (mean of 4) + y2 row norms (f32).
__global__ void reduce_kernel(const float* __restrict__ t, ushort* __restrict__ ybf,
                              float* __restrict__ y2) {
    const int row = blockIdx.x;            // 0..16383
    const int c   = threadIdx.x;           // 0..255
    float4 v = *((const float4*)t + (size_t)row * 256 + c);
    float m = (v.x + v.y + v.z + v.w) * 0.25f;
    ybf[(size_t)row * 256 + c] = __builtin_bit_cast(unsigned short, __float2bfloat16(m));
    float s = m * m;
    #pragma unroll
    for (int o = 32; o > 0; o >>= 1) s += __shfl_down(s, o);
    __shared__ float acc4[4];
    if ((c & 63) == 0) acc4[c >> 6] = s;
    __syncthreads();
    if (c == 0) y2[row] = (acc4[0] + acc4[1]) + (acc4[2] + acc4[3]);
}

// ---------------------------------------------------------------------------
// x row squared norms (x consumed as f32 directly by gemm).
__global__ void rowsq_kernel(const float* __restrict__ src, float* __restrict__ dst) {
    int wave = threadIdx.x >> 6;
    int lane = threadIdx.x & 63;
    int row  = blockIdx.x * 4 + wave;
    const float4* r4 = (const float4*)(src + (size_t)row * D_SZ);
    float4 v = r4[lane];
    float s = v.x*v.x + v.y*v.y + v.z*v.z + v.w*v.w;
    #pragma unroll
    for (int o = 32; o > 0; o >>= 1) s += __shfl_down(s, o);
    if (lane == 0) dst[row] = s;
}

// ---------------------------------------------------------------------------
// bf16 MFMA distance GEMM (no LDS), 8x8-chunk-skew bf16 output:
//   slab s = (i>>3)+(j>>3); element (b*NSLAB+s)*4096 + (i>>3)*64 + (j&7)*8 + (i&7)
//   holds D(i,j) = x2[i] + y2[j] - 2*dot(x_i, y_j), rounded to bf16.
__global__ void __launch_bounds__(256) gemm_kernel(const float* __restrict__ x,
                                                   const ushort* __restrict__ ybf,
                                                   const float* __restrict__ x2,
                                                   const float* __restrict__ y2,
                                                   ushort* __restrict__ Dskew) {
    const int b    = blockIdx.z;
    const int bi   = blockIdx.x;
    const int bj   = blockIdx.y;
    const int w    = threadIdx.x >> 6;
    const int lane = threadIdx.x & 63;
    const int wi   = w & 1, wj = w >> 1;
    const int m    = lane & 15, g = lane >> 4;

    const int i0 = bi * 128 + wi * 64;
    const int j0 = bj * 128 + wj * 64;

    const float*  xb = x   + ((size_t)b * N_SZ + i0 + m) * D_SZ + 8 * g;
    const ushort* yb = ybf + ((size_t)b * M_SZ + j0 + m) * D_SZ + 8 * g;

    f32x4 acc[4][4] = {};

    for (int k0 = 0; k0 < D_SZ; k0 += 32) {
        short8 av[4], bv[4];
        #pragma unroll
        for (int f = 0; f < 4; ++f) {
            av[f] = load_cvt_bf16(xb + (size_t)f * 16 * D_SZ + k0);
            bv[f] = *(const short8*)(yb + (size_t)f * 16 * D_SZ + k0);
        }
        #pragma unroll
        for (int fi = 0; fi < 4; ++fi)
            #pragma unroll
            for (int fj = 0; fj < 4; ++fj)
                acc[fi][fj] = __builtin_amdgcn_mfma_f32_16x16x32_bf16(
                                  av[fi], bv[fj], acc[fi][fj], 0, 0, 0);
    }

    const size_t bbase = (size_t)b * NSLAB * 4096;
    #pragma unroll
    for (int fi = 0; fi < 4; ++fi) {
        const int ib = i0 + fi * 16 + 4 * g;          // 4 consecutive i in one 8-block
        const int L  = ib >> 3;
        const float4 xv = *(const float4*)(x2 + b * N_SZ + ib);
        #pragma unroll
        for (int fj = 0; fj < 4; ++fj) {
            const int j = j0 + fj * 16 + m;
            const float y2v = y2[b * M_SZ + j];
            float d0 = (xv.x + y2v) - 2.0f * acc[fi][fj][0];
            float d1 = (xv.y + y2v) - 2.0f * acc[fi][fj][1];
            float d2 = (xv.z + y2v) - 2.0f * acc[fi][fj][2];
            float d3 = (xv.w + y2v) - 2.0f * acc[fi][fj][3];
            unsigned p0 = pack_bf16(d0, d1);
            unsigned p1 = pack_bf16(d2, d3);
            size_t off = bbase + (size_t)((j >> 3) + L) * 4096
                       + (size_t)L * 64 + (j & 7) * 8 + (ib & 7);
            *(uint2*)(Dskew + off) = make_uint2(p0, p1);
        }
    }
}

// ---------------------------------------------------------------------------
// DTW hard-min DP, min3 form, 8x8 chunks, anti-diagonal SSA dataflow.
// Lane L owns rows 8L..8L+7; chunk t = s - L (cols 8t..8t+7) at step s.
// Per cell: V = d + min3(A,B,C); in-chunk chain = 15 diagonal levels.
// Boundary: 8 shfl_up per step (lane L-1's bottom row, computed 1 step earlier);
// diag corner = pre-update top[7] (lane L-1's chunk t-1, 2 steps earlier).
// PHASE 0 = head (s 0..63): act = t>=0, corner at t==0.
// PHASE 1 = tail (s 64..127): act = t<=63 (s=127 is a full pad step).
template <int PHASE>
__device__ __forceinline__ void dtw_step(int s, int lane,
    const uint4* __restrict__ base, uint4 (&q)[8],
    float (&V)[8], float (&top)[8], float& diag0)
{
    // unpack 64 bf16 -> f32; d[c][r], q[c] holds column c (rows 0..7)
    float d[8][8];
    #pragma unroll
    for (int c = 0; c < 8; ++c) {
        d[c][0] = __uint_as_float(q[c].x << 16);
        d[c][1] = __uint_as_float(q[c].x & 0xFFFF0000u);
        d[c][2] = __uint_as_float(q[c].y << 16);
        d[c][3] = __uint_as_float(q[c].y & 0xFFFF0000u);
        d[c][4] = __uint_as_float(q[c].z << 16);
        d[c][5] = __uint_as_float(q[c].z & 0xFFFF0000u);
        d[c][6] = __uint_as_float(q[c].w << 16);
        d[c][7] = __uint_as_float(q[c].w & 0xFFFF0000u);
    }
    // prefetch slab s+2 into q (2-deep pipeline)
    int sp = s + 2; if (sp > NSLAB - 1) sp = NSLAB - 1;
    const uint4* pp = base + (size_t)sp * SLAB_U4;
    #pragma unroll
    for (int u = 0; u < 8; ++u) q[u] = pp[u];

    float sv[8];
    #pragma unroll
    for (int c = 0; c < 8; ++c) sv[c] = V[7];   // don't-care for inactive lanes

    const bool act = (PHASE == 0) ? (s >= lane) : (s - lane <= 63);

    if (act) {
        float dg0 = diag0;
        if (PHASE == 0) {
            if (s == lane) dg0 = (lane == 0) ? 0.0f : BIGF;  // chunk 0; (0,0) starts at 0
        }
        float n[8][8];
        #pragma unroll
        for (int t = 0; t < 15; ++t) {
            #pragma unroll
            for (int c = 0; c < 8; ++c) {
                const int r = t - c;
                if (r >= 0 && r < 8) {
                    float A  = (r == 0) ? top[c] : n[r-1][c];
                    float Bv = (c == 0) ? V[r]   : n[r][c-1];
                    float Cv = (r == 0) ? ((c == 0) ? dg0    : top[c-1])
                                        : ((c == 0) ? V[r-1] : n[r-1][c-1]);
                    n[r][c] = d[c][r] + fminf(fminf(A, Bv), Cv);
                }
            }
        }
        #pragma unroll
        for (int r = 0; r < 8; ++r) V[r] = n[r][7];
        #pragma unroll
        for (int c = 0; c < 8; ++c) sv[c] = n[7][c];
    }

    // boundary exchange (all lanes execute); save pre-update top[7] as diag
    diag0 = top[7];
    #pragma unroll
    for (int c = 0; c < 8; ++c) {
        float tv = __shfl_up(sv[c], 1);
        top[c] = (lane == 0) ? BIGF : tv;
    }
}

__global__ void __launch_bounds__(64) dtw_kernel(const ushort* __restrict__ Dskew,
                                                 float* __restrict__ partial) {
    const int lane = threadIdx.x;
    const int b    = blockIdx.x;
    const uint4* base = (const uint4*)(Dskew + (size_t)b * NSLAB * 4096) + lane * 8;

    float V[8];
    #pragma unroll
    for (int r = 0; r < 8; ++r) V[r] = BIGF;
    float top[8];
    #pragma unroll
    for (int c = 0; c < 8; ++c) top[c] = BIGF;
    float diag0 = BIGF;     // overridden at t==0

    uint4 qA[8], qB[8];
    #pragma unroll
    for (int u = 0; u < 8; ++u) qA[u] = base[u];
    #pragma unroll
    for (int u = 0; u < 8; ++u) qB[u] = base[SLAB_U4 + u];

    for (int s = 0; s < 64; s += 2) {      // head: t>=0 guard + t==0 corner
        dtw_step<0>(s + 0, lane, base, qA, V, top, diag0);
        dtw_step<0>(s + 1, lane, base, qB, V, top, diag0);
    }
    for (int s = 64; s < 128; s += 2) {    // tail: t<=63 guard (s=127 = pad step)
        dtw_step<1>(s + 0, lane, base, qA, V, top, diag0);
        dtw_step<1>(s + 1, lane, base, qB, V, top, diag0);
    }

    if (lane == 63) partial[b] = V[7];     // cell (511, 511), last active step s=126
}

// ---------------------------------------------------------------------------
__global__ void finalize_kernel(const float* __restrict__ partial, float* __restrict__ out) {
    int lane = threadIdx.x;
    float v = (lane < B_SZ) ? partial[lane] : 0.0f;
    #pragma unroll
    for (int o = 32; o > 0; o >>= 1) v += __shfl_down(v, o);
    if (lane == 0) out[0] = v * (1.0f / B_SZ);
}

// ---------------------------------------------------------------------------
extern "C" void kernel_launch(void* const* d_in, const int* in_sizes, int n_in,
                              void* d_out, int out_size, void* d_ws, size_t ws_size,
                              hipStream_t stream) {
    const float* x  = (const float*)d_in[0];   // (32,512,256)
    const float* te = (const float*)d_in[1];   // (32,512,1024)
    float* out = (float*)d_out;

    char* ws = (char*)d_ws;
    ushort* Dskew = (ushort*)(ws);                                    // 32*128*4096 bf16 = 33.6MB
    ushort* ybf   = (ushort*)(ws + (size_t)B_SZ * NSLAB * 4096 * 2);  // 32*512*256 bf16 = 8.4MB
    float*  x2    = (float*)(ybf + (size_t)B_SZ * M_SZ * D_SZ);
    float*  y2    = x2 + B_SZ * N_SZ;
    float*  part  = y2 + B_SZ * M_SZ;

    reduce_kernel<<<B_SZ * M_SZ, 256, 0, stream>>>(te, ybf, y2);
    rowsq_kernel<<<(B_SZ * N_SZ) / 4, 256, 0, stream>>>(x, x2);
    gemm_kernel<<<dim3(N_SZ/128, M_SZ/128, B_SZ), 256, 0, stream>>>(x, ybf, x2, y2, Dskew);
    dtw_kernel<<<B_SZ, 64, 0, stream>>>(Dskew, part);
    finalize_kernel<<<1, 64, 0, stream>>>(part, out);
}